// Round 2
// baseline (154.713 us; speedup 1.0000x reference)
//
#include <hip/hip_runtime.h>
#include <math.h>

namespace {

constexpr float kA0C0    = 0.8862269254527580f;  // pi / sqrt(4*pi)
constexpr float kA1C1    = 1.7724538509055159f;  // (2*pi/sqrt(3)) * (sqrt(3)/sqrt(4*pi))
constexpr float kA2C2    = 2.4270324670f;        // (2*pi/sqrt(8)) * (3*sqrt(5)/sqrt(12*pi))
constexpr float kAmbient = 0.8f;
constexpr float kInvSigma = 1e4f;   // 1/SIGMA
constexpr float kInvGamma = 1e4f;   // 1/GAMMA
constexpr float kEps     = 1e-10f;
constexpr float kZnear   = 1.0f;
constexpr float kZfar    = 100.0f;
constexpr int   kK       = 8;

// ---- Pass A: per-vertex SH shading -> shaded vertex colors (V x 3 f32) ----
__global__ void shade_verts_kernel(const float* __restrict__ vn,
                                   const float* __restrict__ vc,
                                   const float* __restrict__ sh,
                                   float* __restrict__ vs, int V) {
  int v = blockIdx.x * blockDim.x + threadIdx.x;
  if (v >= V) return;
  float nx = vn[3 * v + 0], ny = vn[3 * v + 1], nz = vn[3 * v + 2];
  float nrm = fmaxf(sqrtf(nx * nx + ny * ny + nz * nz), 1e-6f);
  nx /= nrm; ny /= nrm; nz /= nrm;
  float Y[9];
  Y[0] = kA0C0;
  Y[1] = -kA1C1 * ny;
  Y[2] =  kA1C1 * nz;
  Y[3] = -kA1C1 * nx;
  Y[4] =  kA2C2 * nx * ny;
  Y[5] = -kA2C2 * ny * nz;
  Y[6] =  kA2C2 * (0.5f / 1.7320508075688772f) * (3.0f * nz * nz - 1.0f);
  Y[7] = -kA2C2 * nx * nz;
  Y[8] =  kA2C2 * 0.5f * (nx * nx - ny * ny);
#pragma unroll
  for (int c = 0; c < 3; ++c) {
    float s = Y[0] * (sh[0 * 3 + c] + kAmbient);
#pragma unroll
    for (int n = 1; n < 9; ++n) s += Y[n] * sh[n * 3 + c];
    vs[3 * v + c] = vc[3 * v + c] * s;
  }
}

// ---- Pass B: gather per-face vertex colors, padded to 12 floats (3x float4) ----
// layout: fc[12*f + 4*j + c] = color channel c of vertex j of face f (pad at 4*j+3)
__global__ void face_colors_kernel(const int* __restrict__ faces,
                                   const float* __restrict__ vs,
                                   float4* __restrict__ fc4, int F) {
  int f = blockIdx.x * blockDim.x + threadIdx.x;
  if (f >= F) return;
  int i0 = faces[3 * f + 0], i1 = faces[3 * f + 1], i2 = faces[3 * f + 2];
  fc4[3 * f + 0] = make_float4(vs[3 * i0], vs[3 * i0 + 1], vs[3 * i0 + 2], 0.f);
  fc4[3 * f + 1] = make_float4(vs[3 * i1], vs[3 * i1 + 1], vs[3 * i1 + 2], 0.f);
  fc4[3 * f + 2] = make_float4(vs[3 * i2], vs[3 * i2 + 1], vs[3 * i2 + 2], 0.f);
}

// ---- Pass C: per-pixel softmax RGB blend, 8 lanes per pixel (one per layer) ----
__global__ void __launch_bounds__(256) blend_kernel(
    const float* __restrict__ bary,
    const float* __restrict__ zbuf,
    const float* __restrict__ dists,
    const int* __restrict__ p2f,
    const float4* __restrict__ fc4,
    float4* __restrict__ out, int total) {   // total = P * 8
  int t = blockIdx.x * blockDim.x + threadIdx.x;  // (pixel, layer) pair
  if (t >= total) return;
  int k = t & 7;

  int   f = p2f[t];
  float z = zbuf[t];
  float d = dists[t];
  float b0 = bary[3 * t + 0];
  float b1 = bary[3 * t + 1];
  float b2 = bary[3 * t + 2];

  bool m = f >= 0;
  float pr = m ? __frcp_rn(1.0f + expf(d * kInvSigma)) : 0.0f;
  float zi = m ? (kZfar - z) * (1.0f / (kZfar - kZnear)) : 0.0f;

  // 8-lane group reductions (lane groups aligned: k = lane & 7)
  float maxz = zi;
#pragma unroll
  for (int s = 1; s < 8; s <<= 1) maxz = fmaxf(maxz, __shfl_xor(maxz, s));
  maxz = fmaxf(maxz, kEps);

  float one_m = 1.0f - pr;   // alpha = prod(1 - prob)
#pragma unroll
  for (int s = 1; s < 8; s <<= 1) one_m *= __shfl_xor(one_m, s);

  float w = pr * expf((zi - maxz) * kInvGamma);
  float delta = expf((kEps - maxz) * kInvGamma);

  float cr = 0.0f, cg = 0.0f, cb = 0.0f;
  if (w != 0.0f) {
    const float4* fp = fc4 + 3 * f;
    float4 v0 = fp[0], v1 = fp[1], v2 = fp[2];
    cr = w * (b0 * v0.x + b1 * v1.x + b2 * v2.x);
    cg = w * (b0 * v0.y + b1 * v1.y + b2 * v2.y);
    cb = w * (b0 * v0.z + b1 * v1.z + b2 * v2.z);
  }

  float denom = w;
#pragma unroll
  for (int s = 1; s < 8; s <<= 1) {
    denom += __shfl_xor(denom, s);
    cr    += __shfl_xor(cr, s);
    cg    += __shfl_xor(cg, s);
    cb    += __shfl_xor(cb, s);
  }

  if (k == 0) {
    denom += delta;
    float inv = __frcp_rn(denom);
    float4 o;
    o.x = (cr + delta) * inv;   // BG = (1,1,1)
    o.y = (cg + delta) * inv;
    o.z = (cb + delta) * inv;
    o.w = 1.0f - one_m;
    out[t >> 3] = o;
  }
}

}  // namespace

extern "C" void kernel_launch(void* const* d_in, const int* in_sizes, int n_in,
                              void* d_out, int out_size, void* d_ws, size_t ws_size,
                              hipStream_t stream) {
  const float* vn    = (const float*)d_in[0];
  const float* vc    = (const float*)d_in[1];
  const float* sh    = (const float*)d_in[2];
  const float* bary  = (const float*)d_in[3];
  const float* zbuf  = (const float*)d_in[4];
  const float* dists = (const float*)d_in[5];
  const int*   faces = (const int*)d_in[6];
  const int*   p2f   = (const int*)d_in[7];
  float*       out   = (float*)d_out;

  const int V = in_sizes[0] / 3;
  const int F = in_sizes[6] / 3;
  const int total = in_sizes[4];        // N*H*W*K (= P*8)

  float* vs = (float*)d_ws;
  size_t vsBytes = (size_t)V * 3 * sizeof(float);
  size_t fcOff   = (vsBytes + 255) & ~(size_t)255;
  float4* fc4    = (float4*)((char*)d_ws + fcOff);

  shade_verts_kernel<<<(V + 255) / 256, 256, 0, stream>>>(vn, vc, sh, vs, V);
  face_colors_kernel<<<(F + 255) / 256, 256, 0, stream>>>(faces, vs, fc4, F);
  blend_kernel<<<(total + 255) / 256, 256, 0, stream>>>(
      bary, zbuf, dists, p2f, fc4, (float4*)out, total);
}

// Round 3
// 149.897 us; speedup vs baseline: 1.0321x; 1.0321x over previous
//
#include <hip/hip_runtime.h>
#include <math.h>

typedef float    f4  __attribute__((ext_vector_type(4)));
typedef int      i4  __attribute__((ext_vector_type(4)));
typedef _Float16 hf4 __attribute__((ext_vector_type(4)));

namespace {

constexpr float kA0C0     = 0.8862269254527580f;  // pi / sqrt(4*pi)
constexpr float kA1C1     = 1.7724538509055159f;
constexpr float kA2C2     = 2.4270324670f;
constexpr float kAmbient  = 0.8f;
constexpr float kInvSigma = 1e4f;
constexpr float kInvGamma = 1e4f;
constexpr float kEps      = 1e-10f;
constexpr float kZfar     = 100.0f;
constexpr float kInvZrng  = 1.0f / 99.0f;   // 1/(ZFAR-ZNEAR)

// ---- Pass A: per-face SH shading (redundant per-vertex) -> fp16 face colors ----
// fc[3*f + j] = (r,g,b,0) fp16 of vertex j of face f  (24B/face, 8B-aligned loads)
__global__ void shade_face_kernel(const float* __restrict__ vn,
                                  const float* __restrict__ vc,
                                  const float* __restrict__ sh,
                                  const int* __restrict__ faces,
                                  hf4* __restrict__ fc, int F) {
  int f = blockIdx.x * blockDim.x + threadIdx.x;
  if (f >= F) return;
  float s0r = sh[0] + kAmbient, s0g = sh[1] + kAmbient, s0b = sh[2] + kAmbient;
  int vid[3] = {faces[3 * f + 0], faces[3 * f + 1], faces[3 * f + 2]};
#pragma unroll
  for (int j = 0; j < 3; ++j) {
    int v = vid[j];
    float nx = vn[3 * v + 0], ny = vn[3 * v + 1], nz = vn[3 * v + 2];
    float nrm = fmaxf(sqrtf(nx * nx + ny * ny + nz * nz), 1e-6f);
    nx /= nrm; ny /= nrm; nz /= nrm;
    float Y1 = -kA1C1 * ny, Y2 = kA1C1 * nz, Y3 = -kA1C1 * nx;
    float Y4 =  kA2C2 * nx * ny, Y5 = -kA2C2 * ny * nz;
    float Y6 =  kA2C2 * (0.5f / 1.7320508075688772f) * (3.0f * nz * nz - 1.0f);
    float Y7 = -kA2C2 * nx * nz, Y8 = kA2C2 * 0.5f * (nx * nx - ny * ny);
    float r = kA0C0 * s0r + Y1 * sh[3] + Y2 * sh[6]  + Y3 * sh[9]  + Y4 * sh[12]
            + Y5 * sh[15] + Y6 * sh[18] + Y7 * sh[21] + Y8 * sh[24];
    float g = kA0C0 * s0g + Y1 * sh[4] + Y2 * sh[7]  + Y3 * sh[10] + Y4 * sh[13]
            + Y5 * sh[16] + Y6 * sh[19] + Y7 * sh[22] + Y8 * sh[25];
    float b = kA0C0 * s0b + Y1 * sh[5] + Y2 * sh[8]  + Y3 * sh[11] + Y4 * sh[14]
            + Y5 * sh[17] + Y6 * sh[20] + Y7 * sh[23] + Y8 * sh[26];
    hf4 o;
    o.x = (_Float16)(vc[3 * v + 0] * r);
    o.y = (_Float16)(vc[3 * v + 1] * g);
    o.z = (_Float16)(vc[3 * v + 2] * b);
    o.w = (_Float16)0.0f;
    fc[3 * f + j] = o;
  }
}

// ---- Pass B: per-pixel softmax blend; bary + color gather only where w != 0 ----
__global__ void __launch_bounds__(256) blend_kernel(
    const float* __restrict__ bary,
    const f4* __restrict__ zb4,
    const f4* __restrict__ ds4,
    const i4* __restrict__ pf4,
    const hf4* __restrict__ fc,
    f4* __restrict__ out, int P) {
  int p = blockIdx.x * blockDim.x + threadIdx.x;
  if (p >= P) return;

  i4 fA = __builtin_nontemporal_load(pf4 + 2 * p);
  i4 fB = __builtin_nontemporal_load(pf4 + 2 * p + 1);
  f4 zA = __builtin_nontemporal_load(zb4 + 2 * p);
  f4 zB = __builtin_nontemporal_load(zb4 + 2 * p + 1);
  f4 dA = __builtin_nontemporal_load(ds4 + 2 * p);
  f4 dB = __builtin_nontemporal_load(ds4 + 2 * p + 1);
  int   fk[8] = {fA.x, fA.y, fA.z, fA.w, fB.x, fB.y, fB.z, fB.w};
  float z[8]  = {zA.x, zA.y, zA.z, zA.w, zB.x, zB.y, zB.z, zB.w};
  float d[8]  = {dA.x, dA.y, dA.z, dA.w, dB.x, dB.y, dB.z, dB.w};

  float pr[8], zi[8];
  float maxz = kEps, alpha = 1.0f;
#pragma unroll
  for (int k = 0; k < 8; ++k) {
    bool m = fk[k] >= 0;
    float e = __expf(d[k] * kInvSigma);
    float prv = m ? 1.0f / (1.0f + e) : 0.0f;   // sigmoid(-d/SIGMA)
    pr[k] = prv;
    alpha *= 1.0f - prv;
    float zv = m ? (kZfar - z[k]) * kInvZrng : 0.0f;
    zi[k] = zv;
    maxz = fmaxf(maxz, zv);
  }

  float delta = __expf((kEps - maxz) * kInvGamma);
  float denom = delta;
  float cr = 0.0f, cg = 0.0f, cb = 0.0f;
#pragma unroll
  for (int k = 0; k < 8; ++k) {
    float w = pr[k] * __expf((zi[k] - maxz) * kInvGamma);
    denom += w;
    if (w != 0.0f) {                            // ~1.06 of 8 layers
      int t = 8 * p + k;
      float b0 = bary[3 * t + 0], b1 = bary[3 * t + 1], b2 = bary[3 * t + 2];
      hf4 v0 = fc[3 * fk[k] + 0];
      hf4 v1 = fc[3 * fk[k] + 1];
      hf4 v2 = fc[3 * fk[k] + 2];
      cr += w * (b0 * (float)v0.x + b1 * (float)v1.x + b2 * (float)v2.x);
      cg += w * (b0 * (float)v0.y + b1 * (float)v1.y + b2 * (float)v2.y);
      cb += w * (b0 * (float)v0.z + b1 * (float)v1.z + b2 * (float)v2.z);
    }
  }

  f4 o;
  o.x = (cr + delta) / denom;   // BG = (1,1,1)
  o.y = (cg + delta) / denom;
  o.z = (cb + delta) / denom;
  o.w = 1.0f - alpha;
  __builtin_nontemporal_store(o, out + p);
}

}  // namespace

extern "C" void kernel_launch(void* const* d_in, const int* in_sizes, int n_in,
                              void* d_out, int out_size, void* d_ws, size_t ws_size,
                              hipStream_t stream) {
  const float* vn    = (const float*)d_in[0];
  const float* vc    = (const float*)d_in[1];
  const float* sh    = (const float*)d_in[2];
  const float* bary  = (const float*)d_in[3];
  const float* zbuf  = (const float*)d_in[4];
  const float* dists = (const float*)d_in[5];
  const int*   faces = (const int*)d_in[6];
  const int*   p2f   = (const int*)d_in[7];

  const int F = in_sizes[6] / 3;
  const int P = in_sizes[4] / 8;   // N*H*W pixels (K = 8)

  hf4* fc = (hf4*)d_ws;            // F * 24B = 4.8 MB

  shade_face_kernel<<<(F + 255) / 256, 256, 0, stream>>>(vn, vc, sh, faces, fc, F);
  blend_kernel<<<(P + 255) / 256, 256, 0, stream>>>(
      bary, (const f4*)zbuf, (const f4*)dists, (const i4*)p2f, fc, (f4*)d_out, P);
}